// Round 3
// baseline (447.680 us; speedup 1.0000x reference)
//
#include <hip/hip_runtime.h>
#include <math.h>

using bf16x8  = __attribute__((ext_vector_type(8))) __bf16;
using floatx4 = __attribute__((ext_vector_type(4))) float;
using ushortx8 = __attribute__((ext_vector_type(8))) unsigned short;
typedef unsigned short u16;

__device__ __forceinline__ float bf2f(u16 u) {
  unsigned int x = ((unsigned int)u) << 16;
  return __builtin_bit_cast(float, x);
}
__device__ __forceinline__ u16 f2bf(float f) {
  unsigned int x = __builtin_bit_cast(unsigned int, f);
  x += 0x7FFFu + ((x >> 16) & 1u);   // round-to-nearest-even
  return (u16)(x >> 16);
}

// ---------------- x: fp32 -> bf16 ----------------
__global__ __launch_bounds__(256) void cvt_kernel(const float* __restrict__ x, u16* __restrict__ xb) {
  int g = (blockIdx.x * 256 + threadIdx.x) * 8;
  float4 a = *(const float4*)(x + g);
  float4 b = *(const float4*)(x + g + 4);
  ushortx8 o;
  o[0] = f2bf(a.x); o[1] = f2bf(a.y); o[2] = f2bf(a.z); o[3] = f2bf(a.w);
  o[4] = f2bf(b.x); o[5] = f2bf(b.y); o[6] = f2bf(b.z); o[7] = f2bf(b.w);
  *(ushortx8*)(xb + g) = o;
}

// ---------------- weight scale: sum |W| (fp32 in, two-stage, deterministic) ----------------
__global__ __launch_bounds__(256) void absum_kernel(const float* W0, const float* W1,
                                                    const float* W2, const float* W3,
                                                    float* partials) {
  const float* W = (blockIdx.y == 0) ? W0 : (blockIdx.y == 1) ? W1 : (blockIdx.y == 2) ? W2 : W3;
  int tid = threadIdx.x;
  int base = blockIdx.x * 16384 + tid;
  float s = 0.f;
#pragma unroll
  for (int i = 0; i < 64; ++i) s += fabsf(W[base + i * 256]);
  __shared__ float red[256];
  red[tid] = s;
  __syncthreads();
  for (int off = 128; off > 0; off >>= 1) {
    if (tid < off) red[tid] += red[tid + off];
    __syncthreads();
  }
  if (tid == 0) partials[blockIdx.y * 64 + blockIdx.x] = red[0];
}

__global__ void scales_kernel(const float* partials, float* scales) {
  int w = threadIdx.x;
  if (w < 4) {
    float s = 0.f;
    for (int i = 0; i < 64; ++i) s += partials[w * 64 + i];
    scales[w] = s * (1.f / 1048576.f);  // mean |W| over 1024*1024
  }
}

// ---------------- ternary quantize: Wt in {-1,0,+1} (exact in bf16) ----------------
__global__ __launch_bounds__(256) void quant_kernel(const float* W0, const float* W1,
                                                    const float* W2, const float* W3,
                                                    const float* scales, u16* Wt) {
  int w = blockIdx.y;
  const float* W = (w == 0) ? W0 : (w == 1) ? W1 : (w == 2) ? W2 : W3;
  u16* O = Wt + (size_t)w * (1u << 20);
  float s = scales[w] + 1e-8f;
  int e = blockIdx.x * 256 + threadIdx.x;
  float t = W[e] / s;
  t = fminf(fmaxf(t, -1.f), 1.f);
  O[e] = f2bf(rintf(t));  // -1/0/+1 exact; scale applied in GEMM epilogue
}

// ---------------- GEMM: C[M,N] = (A[M,K] * B[N,K]^T) * scale ----------------
// OUT_F32: write fp32 (for final projection into d_out), else bf16
#define GLD 72  // 64 + 8 pad: row stride 144B -> 2-way LDS aliasing (free)
template <bool OUT_F32>
__global__ __launch_bounds__(256) void gemm_bt(const u16* __restrict__ A, const u16* __restrict__ B,
                                               void* __restrict__ Cv, int M, int N, int K,
                                               const float* __restrict__ scale_ptr) {
  __shared__ __align__(16) u16 As[64][GLD];
  __shared__ __align__(16) u16 Bs[64][GLD];
  int tid = threadIdx.x;
  int wave = tid >> 6, lane = tid & 63;
  int quad = lane >> 4, l16 = lane & 15;
  int bm = blockIdx.x * 64, bn = blockIdx.y * 64;
  int wm = (wave >> 1) * 32, wn = (wave & 1) * 32;  // wave tile origin (local)
  floatx4 acc[2][2] = {};
  int r = tid >> 2, c4 = (tid & 3) << 4;
  const u16* ga = A + (size_t)(bm + r) * K + c4;
  const u16* gb = B + (size_t)(bn + r) * K + c4;
  for (int k0 = 0; k0 < K; k0 += 64) {
    *(ushortx8*)&As[r][c4]     = *(const ushortx8*)(ga);
    *(ushortx8*)&As[r][c4 + 8] = *(const ushortx8*)(ga + 8);
    *(ushortx8*)&Bs[r][c4]     = *(const ushortx8*)(gb);
    *(ushortx8*)&Bs[r][c4 + 8] = *(const ushortx8*)(gb + 8);
    ga += 64; gb += 64;
    __syncthreads();
#pragma unroll
    for (int kk = 0; kk < 64; kk += 32) {
      bf16x8 a0 = __builtin_bit_cast(bf16x8, *(const ushortx8*)&As[wm + l16][kk + quad * 8]);
      bf16x8 a1 = __builtin_bit_cast(bf16x8, *(const ushortx8*)&As[wm + 16 + l16][kk + quad * 8]);
      bf16x8 b0 = __builtin_bit_cast(bf16x8, *(const ushortx8*)&Bs[wn + l16][kk + quad * 8]);
      bf16x8 b1 = __builtin_bit_cast(bf16x8, *(const ushortx8*)&Bs[wn + 16 + l16][kk + quad * 8]);
      acc[0][0] = __builtin_amdgcn_mfma_f32_16x16x32_bf16(a0, b0, acc[0][0], 0, 0, 0);
      acc[0][1] = __builtin_amdgcn_mfma_f32_16x16x32_bf16(a0, b1, acc[0][1], 0, 0, 0);
      acc[1][0] = __builtin_amdgcn_mfma_f32_16x16x32_bf16(a1, b0, acc[1][0], 0, 0, 0);
      acc[1][1] = __builtin_amdgcn_mfma_f32_16x16x32_bf16(a1, b1, acc[1][1], 0, 0, 0);
    }
    __syncthreads();
  }
  float sc = scale_ptr[0];
#pragma unroll
  for (int i = 0; i < 2; ++i)
#pragma unroll
    for (int j = 0; j < 2; ++j)
#pragma unroll
      for (int rg = 0; rg < 4; ++rg) {
        int row = bm + wm + i * 16 + quad * 4 + rg;   // C/D: row = quad*4+reg
        int col = bn + wn + j * 16 + l16;             // C/D: col = lane&15
        if (OUT_F32)
          ((float*)Cv)[(size_t)row * N + col] = acc[i][j][rg] * sc;
        else
          ((u16*)Cv)[(size_t)row * N + col] = f2bf(acc[i][j][rg] * sc);
      }
}

// ---------------- RoPE (in-place on q,k); folds 1/sqrt(64)=0.125 into q ----------------
__global__ __launch_bounds__(256) void rope_kernel(u16* q, u16* k) {
  int gid = blockIdx.x * 256 + threadIdx.x;  // B*T*H*32 threads
  int i = gid & 31;
  int h = (gid >> 5) & 15;
  int bt = gid >> 9;          // 0..4095
  int t = bt & 2047;
  float inv = exp2f(-(float)i * (13.287712379549449f / 32.f));  // 10000^(-i/32)
  float ang = (float)t * inv;
  float s = sinf(ang), c = cosf(ang);
  int row = bt * 1024 + h * 64;
  float q1 = bf2f(q[row + i]), q2 = bf2f(q[row + i + 32]);
  q[row + i]      = f2bf((q1 * c - q2 * s) * 0.125f);
  q[row + i + 32] = f2bf((q2 * c + q1 * s) * 0.125f);
  float k1 = bf2f(k[row + i]), k2 = bf2f(k[row + i + 32]);
  k[row + i]      = f2bf(k1 * c - k2 * s);
  k[row + i + 32] = f2bf(k2 * c + k1 * s);
}

// ---------------- causal flash attention: 64-q block (4 waves x 16q), 32-key tiles ----------------
__global__ __launch_bounds__(256) void attn_kernel(const u16* __restrict__ q, const u16* __restrict__ k,
                                                   const u16* __restrict__ v, u16* __restrict__ y) {
  __shared__ __align__(16) u16 Ks[32][72];     // [key][d]
  __shared__ __align__(16) u16 Vt[64][40];     // [d][key]  (transposed for B-frag)
  __shared__ __align__(16) u16 Ps[4][16][40];  // per-wave P round-trip [q][key]
  const int T = 2048, C = 1024;
  int tid = threadIdx.x;
  int wave = tid >> 6, lane = tid & 63;
  int quad = lane >> 4, l16 = lane & 15;
  int q0 = blockIdx.x * 64;
  int bh = blockIdx.y, b = bh >> 4, h = bh & 15;
  int wq0 = q0 + wave * 16;

  const u16* gq = q + (size_t)(b * T + wq0 + l16) * C + h * 64 + quad * 8;
  bf16x8 aq0 = __builtin_bit_cast(bf16x8, *(const ushortx8*)(gq));       // d in [0,32)
  bf16x8 aq1 = __builtin_bit_cast(bf16x8, *(const ushortx8*)(gq + 32));  // d in [32,64)

  float mrun[4], lrun[4];
  floatx4 o[4] = {};
#pragma unroll
  for (int rg = 0; rg < 4; ++rg) { mrun[rg] = -__builtin_inff(); lrun[rg] = 0.f; }

  int nkt = blockIdx.x * 2 + 2;  // key tiles of 32 covering [0, q0+64)
  int sr = tid >> 3, sc = (tid & 7) << 3;
  for (int kt = 0; kt < nkt; ++kt) {
    int kb = kt * 32;
    const u16* gk = k + (size_t)(b * T + kb + sr) * C + h * 64 + sc;
    *(ushortx8*)&Ks[sr][sc] = *(const ushortx8*)gk;
    const u16* gv = v + (size_t)(b * T + kb + sr) * C + h * 64 + sc;
    ushortx8 vv = *(const ushortx8*)gv;
#pragma unroll
    for (int j = 0; j < 8; ++j) Vt[sc + j][sr] = vv[j];
    __syncthreads();

    // S = Q K^T  (scale pre-folded into q)
    floatx4 sacc[2] = {};
#pragma unroll
    for (int nt = 0; nt < 2; ++nt) {
      bf16x8 bk0 = __builtin_bit_cast(bf16x8, *(const ushortx8*)&Ks[nt * 16 + l16][quad * 8]);
      bf16x8 bk1 = __builtin_bit_cast(bf16x8, *(const ushortx8*)&Ks[nt * 16 + l16][32 + quad * 8]);
      sacc[nt] = __builtin_amdgcn_mfma_f32_16x16x32_bf16(aq0, bk0, sacc[nt], 0, 0, 0);
      sacc[nt] = __builtin_amdgcn_mfma_f32_16x16x32_bf16(aq1, bk1, sacc[nt], 0, 0, 0);
    }

    float alpha[4];
#pragma unroll
    for (int rg = 0; rg < 4; ++rg) {
      int qr = wq0 + quad * 4 + rg;
#pragma unroll
      for (int nt = 0; nt < 2; ++nt) {
        int key = kb + nt * 16 + l16;
        if (key > qr) sacc[nt][rg] = -__builtin_inff();  // causal mask
      }
      float mx = fmaxf(fmaxf(sacc[0][rg], sacc[1][rg]), mrun[rg]);
#pragma unroll
      for (int d = 1; d < 16; d <<= 1) mx = fmaxf(mx, __shfl_xor(mx, d, 64));
      alpha[rg] = expf(mrun[rg] - mx);  // mrun=-inf -> 0; fully-masked tile -> mx=mrun -> 1
      float p0 = expf(sacc[0][rg] - mx);
      float p1 = expf(sacc[1][rg] - mx);
      float rs = p0 + p1;
#pragma unroll
      for (int d = 1; d < 16; d <<= 1) rs += __shfl_xor(rs, d, 64);
      lrun[rg] = lrun[rg] * alpha[rg] + rs;
      mrun[rg] = mx;
      Ps[wave][quad * 4 + rg][l16]      = f2bf(p0);
      Ps[wave][quad * 4 + rg][16 + l16] = f2bf(p1);
    }
    __syncthreads();  // P writes -> A-frag reads (and Vt stage visibility)

#pragma unroll
    for (int nt = 0; nt < 4; ++nt)
#pragma unroll
      for (int rg = 0; rg < 4; ++rg) o[nt][rg] *= alpha[rg];

    bf16x8 ap = __builtin_bit_cast(bf16x8, *(const ushortx8*)&Ps[wave][l16][quad * 8]);
#pragma unroll
    for (int nt = 0; nt < 4; ++nt) {
      bf16x8 bv = __builtin_bit_cast(bf16x8, *(const ushortx8*)&Vt[nt * 16 + l16][quad * 8]);
      o[nt] = __builtin_amdgcn_mfma_f32_16x16x32_bf16(ap, bv, o[nt], 0, 0, 0);
    }
    __syncthreads();  // protect Ks/Vt before next stage
  }

#pragma unroll
  for (int nt = 0; nt < 4; ++nt)
#pragma unroll
    for (int rg = 0; rg < 4; ++rg) {
      int qg = wq0 + quad * 4 + rg;
      int col = h * 64 + nt * 16 + l16;
      y[(size_t)(b * T + qg) * C + col] = f2bf(o[nt][rg] / lrun[rg]);
    }
}

extern "C" void kernel_launch(void* const* d_in, const int* in_sizes, int n_in,
                              void* d_out, int out_size, void* d_ws, size_t ws_size,
                              hipStream_t stream) {
  const float* x  = (const float*)d_in[0];
  const float* Wq = (const float*)d_in[1];
  const float* Wk = (const float*)d_in[2];
  const float* Wv = (const float*)d_in[3];
  const float* Wo = (const float*)d_in[4];
  // d_in[5] = mask: known causal tril, handled analytically

  char* ws = (char*)d_ws;
  float* partials = (float*)ws;             // 256 floats
  float* scales   = (float*)(ws + 1024);    // 4 floats
  u16* Wt = (u16*)(ws + 4096);              // 4 x 1M bf16 (ternary)
  u16* xb = (u16*)(ws + 4096 + (size_t)(8u << 20));   // x in bf16 (4M elems)
  u16* qb = xb + (4u << 20);
  u16* kb = qb + (4u << 20);
  u16* vb = kb + (4u << 20);
  u16* yb = vb + (4u << 20);
  float* out = (float*)d_out;  // reference output dtype is float32

  cvt_kernel<<<2048, 256, 0, stream>>>(x, xb);
  absum_kernel<<<dim3(64, 4), 256, 0, stream>>>(Wq, Wk, Wv, Wo, partials);
  scales_kernel<<<1, 64, 0, stream>>>(partials, scales);
  quant_kernel<<<dim3(4096, 4), 256, 0, stream>>>(Wq, Wk, Wv, Wo, scales, Wt);

  const int M = 4096, N = 1024, K = 1024;
  gemm_bt<false><<<dim3(64, 16), 256, 0, stream>>>(xb, Wt + 0 * (1u << 20), qb, M, N, K, scales + 0);
  gemm_bt<false><<<dim3(64, 16), 256, 0, stream>>>(xb, Wt + 1 * (1u << 20), kb, M, N, K, scales + 1);
  gemm_bt<false><<<dim3(64, 16), 256, 0, stream>>>(xb, Wt + 2 * (1u << 20), vb, M, N, K, scales + 2);
  rope_kernel<<<8192, 256, 0, stream>>>(qb, kb);
  attn_kernel<<<dim3(32, 32), 256, 0, stream>>>(qb, kb, vb, yb);
  gemm_bt<true><<<dim3(64, 16), 256, 0, stream>>>(yb, Wt + 3 * (1u << 20), out, M, N, K, scales + 3);
}

// Round 4
// 345.776 us; speedup vs baseline: 1.2947x; 1.2947x over previous
//
#include <hip/hip_runtime.h>
#include <math.h>

using bf16x8  = __attribute__((ext_vector_type(8))) __bf16;
using floatx4 = __attribute__((ext_vector_type(4))) float;
using ushortx8 = __attribute__((ext_vector_type(8))) unsigned short;
typedef unsigned short u16;

__device__ __forceinline__ float bf2f(u16 u) {
  unsigned int x = ((unsigned int)u) << 16;
  return __builtin_bit_cast(float, x);
}
__device__ __forceinline__ u16 f2bf(float f) {
  unsigned int x = __builtin_bit_cast(unsigned int, f);
  x += 0x7FFFu + ((x >> 16) & 1u);   // round-to-nearest-even
  return (u16)(x >> 16);
}

// ---------------- x: fp32 -> bf16 ----------------
__global__ __launch_bounds__(256) void cvt_kernel(const float* __restrict__ x, u16* __restrict__ xb) {
  int g = (blockIdx.x * 256 + threadIdx.x) * 8;
  float4 a = *(const float4*)(x + g);
  float4 b = *(const float4*)(x + g + 4);
  ushortx8 o;
  o[0] = f2bf(a.x); o[1] = f2bf(a.y); o[2] = f2bf(a.z); o[3] = f2bf(a.w);
  o[4] = f2bf(b.x); o[5] = f2bf(b.y); o[6] = f2bf(b.z); o[7] = f2bf(b.w);
  *(ushortx8*)(xb + g) = o;
}

// ---------------- weight scale: sum |W| (fp32 in, two-stage, deterministic) ----------------
__global__ __launch_bounds__(256) void absum_kernel(const float* W0, const float* W1,
                                                    const float* W2, const float* W3,
                                                    float* partials) {
  const float* W = (blockIdx.y == 0) ? W0 : (blockIdx.y == 1) ? W1 : (blockIdx.y == 2) ? W2 : W3;
  int tid = threadIdx.x;
  int base = blockIdx.x * 16384 + tid;
  float s = 0.f;
#pragma unroll
  for (int i = 0; i < 64; ++i) s += fabsf(W[base + i * 256]);
  __shared__ float red[256];
  red[tid] = s;
  __syncthreads();
  for (int off = 128; off > 0; off >>= 1) {
    if (tid < off) red[tid] += red[tid + off];
    __syncthreads();
  }
  if (tid == 0) partials[blockIdx.y * 64 + blockIdx.x] = red[0];
}

__global__ void scales_kernel(const float* partials, float* scales) {
  int w = threadIdx.x;
  if (w < 4) {
    float s = 0.f;
    for (int i = 0; i < 64; ++i) s += partials[w * 64 + i];
    scales[w] = s * (1.f / 1048576.f);  // mean |W| over 1024*1024
  }
}

// ---------------- ternary quantize: Wt in {-1,0,+1} (exact in bf16) ----------------
__global__ __launch_bounds__(256) void quant_kernel(const float* W0, const float* W1,
                                                    const float* W2, const float* W3,
                                                    const float* scales, u16* Wt) {
  int w = blockIdx.y;
  const float* W = (w == 0) ? W0 : (w == 1) ? W1 : (w == 2) ? W2 : W3;
  u16* O = Wt + (size_t)w * (1u << 20);
  float s = scales[w] + 1e-8f;
  int e = blockIdx.x * 256 + threadIdx.x;
  float t = W[e] / s;
  t = fminf(fmaxf(t, -1.f), 1.f);
  O[e] = f2bf(rintf(t));  // -1/0/+1 exact; scale applied in GEMM epilogue
}

// ---------------- GEMM: C[M,N] = (A[M,K] * B[N,K]^T) * scale ----------------
#define GLD 72  // 64 + 8 pad
template <bool OUT_F32>
__global__ __launch_bounds__(256) void gemm_bt(const u16* __restrict__ A, const u16* __restrict__ B,
                                               void* __restrict__ Cv, int M, int N, int K,
                                               const float* __restrict__ scale_ptr) {
  __shared__ __align__(16) u16 As[64][GLD];
  __shared__ __align__(16) u16 Bs[64][GLD];
  int tid = threadIdx.x;
  int wave = tid >> 6, lane = tid & 63;
  int quad = lane >> 4, l16 = lane & 15;
  int bm = blockIdx.x * 64, bn = blockIdx.y * 64;
  int wm = (wave >> 1) * 32, wn = (wave & 1) * 32;
  floatx4 acc[2][2] = {};
  int r = tid >> 2, c4 = (tid & 3) << 4;
  const u16* ga = A + (size_t)(bm + r) * K + c4;
  const u16* gb = B + (size_t)(bn + r) * K + c4;
  for (int k0 = 0; k0 < K; k0 += 64) {
    *(ushortx8*)&As[r][c4]     = *(const ushortx8*)(ga);
    *(ushortx8*)&As[r][c4 + 8] = *(const ushortx8*)(ga + 8);
    *(ushortx8*)&Bs[r][c4]     = *(const ushortx8*)(gb);
    *(ushortx8*)&Bs[r][c4 + 8] = *(const ushortx8*)(gb + 8);
    ga += 64; gb += 64;
    __syncthreads();
#pragma unroll
    for (int kk = 0; kk < 64; kk += 32) {
      bf16x8 a0 = __builtin_bit_cast(bf16x8, *(const ushortx8*)&As[wm + l16][kk + quad * 8]);
      bf16x8 a1 = __builtin_bit_cast(bf16x8, *(const ushortx8*)&As[wm + 16 + l16][kk + quad * 8]);
      bf16x8 b0 = __builtin_bit_cast(bf16x8, *(const ushortx8*)&Bs[wn + l16][kk + quad * 8]);
      bf16x8 b1 = __builtin_bit_cast(bf16x8, *(const ushortx8*)&Bs[wn + 16 + l16][kk + quad * 8]);
      acc[0][0] = __builtin_amdgcn_mfma_f32_16x16x32_bf16(a0, b0, acc[0][0], 0, 0, 0);
      acc[0][1] = __builtin_amdgcn_mfma_f32_16x16x32_bf16(a0, b1, acc[0][1], 0, 0, 0);
      acc[1][0] = __builtin_amdgcn_mfma_f32_16x16x32_bf16(a1, b0, acc[1][0], 0, 0, 0);
      acc[1][1] = __builtin_amdgcn_mfma_f32_16x16x32_bf16(a1, b1, acc[1][1], 0, 0, 0);
    }
    __syncthreads();
  }
  float sc = scale_ptr[0];
#pragma unroll
  for (int i = 0; i < 2; ++i)
#pragma unroll
    for (int j = 0; j < 2; ++j)
#pragma unroll
      for (int rg = 0; rg < 4; ++rg) {
        int row = bm + wm + i * 16 + quad * 4 + rg;
        int col = bn + wn + j * 16 + l16;
        if (OUT_F32)
          ((float*)Cv)[(size_t)row * N + col] = acc[i][j][rg] * sc;
        else
          ((u16*)Cv)[(size_t)row * N + col] = f2bf(acc[i][j][rg] * sc);
      }
}

// ---------------- RoPE (in-place on q,k); folds 1/sqrt(64)=0.125 into q ----------------
__global__ __launch_bounds__(256) void rope_kernel(u16* q, u16* k) {
  int gid = blockIdx.x * 256 + threadIdx.x;  // B*T*H*32 threads
  int i = gid & 31;
  int h = (gid >> 5) & 15;
  int bt = gid >> 9;          // 0..4095
  int t = bt & 2047;
  float inv = exp2f(-(float)i * (13.287712379549449f / 32.f));  // 10000^(-i/32)
  float ang = (float)t * inv;
  float s = __sinf(ang), c = __cosf(ang);  // v_sin/v_cos: ~2e-4 abs err << bf16 rounding
  int row = bt * 1024 + h * 64;
  float q1 = bf2f(q[row + i]), q2 = bf2f(q[row + i + 32]);
  q[row + i]      = f2bf((q1 * c - q2 * s) * 0.125f);
  q[row + i + 32] = f2bf((q2 * c + q1 * s) * 0.125f);
  float k1 = bf2f(k[row + i]), k2 = bf2f(k[row + i + 32]);
  k[row + i]      = f2bf(k1 * c - k2 * s);
  k[row + i + 32] = f2bf(k2 * c + k1 * s);
}

// ---------------- causal flash attention v2 ----------------
// 64-q block (4 waves x 16q), 64-key tiles, double-buffered K/V (1 barrier/tile),
// log2-space softmax (native v_exp_f32), conflict-free transposed V staging.
__global__ __launch_bounds__(256) void attn_kernel(const u16* __restrict__ q, const u16* __restrict__ k,
                                                   const u16* __restrict__ v, u16* __restrict__ y) {
  __shared__ __align__(16) u16 Ks[2][64][72];   // [buf][key][d]
  __shared__ __align__(16) u16 Vt[2][64][72];   // [buf][d][key]
  __shared__ __align__(16) u16 Ps[4][16][72];   // per-wave P: [q][key] (same-wave roundtrip, no barrier)
  const int T = 2048, C = 1024;
  const float L2E = 1.4426950408889634f;
  int tid = threadIdx.x;
  int wave = tid >> 6, lane = tid & 63;
  int quad = lane >> 4, l16 = lane & 15;
  int qblock = (int)gridDim.x - 1 - (int)blockIdx.x;  // heavy blocks dispatch first
  int q0 = qblock * 64;
  int b = blockIdx.y >> 4, h = blockIdx.y & 15;
  int wq0 = q0 + wave * 16;

  const u16* gq = q + (size_t)(b * T + wq0 + l16) * C + h * 64 + quad * 8;
  bf16x8 aq0 = __builtin_bit_cast(bf16x8, *(const ushortx8*)(gq));       // d [0,32)
  bf16x8 aq1 = __builtin_bit_cast(bf16x8, *(const ushortx8*)(gq + 32));  // d [32,64)

  // staging: K -> rows (4 lanes x 16B = 64B contiguous per row); V -> transposed, key=lane (conflict-free)
  int kkey = tid >> 2, kd = (tid & 3) << 4;
  const u16* kbase = k + (size_t)(b * T + kkey) * C + h * 64 + kd;
  const u16* vbase = v + (size_t)(b * T + lane) * C + h * 64 + wave * 16;

  float mrun[4], lrun[4];
  floatx4 o[4] = {};
#pragma unroll
  for (int rg = 0; rg < 4; ++rg) { mrun[rg] = -__builtin_inff(); lrun[rg] = 0.f; }

  int nkt = qblock + 1;

  // stage tile 0
  ushortx8 kr0 = *(const ushortx8*)(kbase);
  ushortx8 kr1 = *(const ushortx8*)(kbase + 8);
  ushortx8 vr0 = *(const ushortx8*)(vbase);
  ushortx8 vr1 = *(const ushortx8*)(vbase + 8);
  *(ushortx8*)&Ks[0][kkey][kd]     = kr0;
  *(ushortx8*)&Ks[0][kkey][kd + 8] = kr1;
#pragma unroll
  for (int j = 0; j < 8; ++j) Vt[0][wave * 16 + j][lane] = vr0[j];
#pragma unroll
  for (int j = 0; j < 8; ++j) Vt[0][wave * 16 + 8 + j][lane] = vr1[j];
  __syncthreads();

  for (int kt = 0; kt < nkt; ++kt) {
    int cur = kt & 1;
    bool haveNext = (kt + 1) < nkt;
    if (haveNext) {  // prefetch next tile into regs (latency hidden under compute)
      const u16* kn = kbase + (size_t)(kt + 1) * 64 * C;
      const u16* vn = vbase + (size_t)(kt + 1) * 64 * C;
      kr0 = *(const ushortx8*)(kn);
      kr1 = *(const ushortx8*)(kn + 8);
      vr0 = *(const ushortx8*)(vn);
      vr1 = *(const ushortx8*)(vn + 8);
    }

    // S = Q K^T (1/sqrt(D) pre-folded into q)
    floatx4 sacc[4] = {};
#pragma unroll
    for (int nt = 0; nt < 4; ++nt) {
      bf16x8 bk0 = __builtin_bit_cast(bf16x8, *(const ushortx8*)&Ks[cur][nt * 16 + l16][quad * 8]);
      bf16x8 bk1 = __builtin_bit_cast(bf16x8, *(const ushortx8*)&Ks[cur][nt * 16 + l16][32 + quad * 8]);
      sacc[nt] = __builtin_amdgcn_mfma_f32_16x16x32_bf16(aq0, bk0, sacc[nt], 0, 0, 0);
      sacc[nt] = __builtin_amdgcn_mfma_f32_16x16x32_bf16(aq1, bk1, sacc[nt], 0, 0, 0);
    }

    bool last = (kt == nkt - 1);  // only the diagonal tile needs masking
    float alpha[4];
#pragma unroll
    for (int rg = 0; rg < 4; ++rg) {
      float s0 = sacc[0][rg] * L2E, s1 = sacc[1][rg] * L2E;
      float s2 = sacc[2][rg] * L2E, s3 = sacc[3][rg] * L2E;
      if (last) {
        int qr = wq0 + quad * 4 + rg;
        int key = kt * 64 + l16;
        if (key      > qr) s0 = -__builtin_inff();
        if (key + 16 > qr) s1 = -__builtin_inff();
        if (key + 32 > qr) s2 = -__builtin_inff();
        if (key + 48 > qr) s3 = -__builtin_inff();
      }
      float mx = fmaxf(fmaxf(s0, s1), fmaxf(s2, s3));
      mx = fmaxf(mx, mrun[rg]);
#pragma unroll
      for (int d = 1; d < 16; d <<= 1) mx = fmaxf(mx, __shfl_xor(mx, d, 64));
      alpha[rg] = exp2f(mrun[rg] - mx);  // -inf -> 0 on first tile
      float p0 = exp2f(s0 - mx), p1 = exp2f(s1 - mx);
      float p2 = exp2f(s2 - mx), p3 = exp2f(s3 - mx);
      float rs = (p0 + p1) + (p2 + p3);
#pragma unroll
      for (int d = 1; d < 16; d <<= 1) rs += __shfl_xor(rs, d, 64);
      lrun[rg] = lrun[rg] * alpha[rg] + rs;
      mrun[rg] = mx;
      Ps[wave][quad * 4 + rg][l16]      = f2bf(p0);
      Ps[wave][quad * 4 + rg][16 + l16] = f2bf(p1);
      Ps[wave][quad * 4 + rg][32 + l16] = f2bf(p2);
      Ps[wave][quad * 4 + rg][48 + l16] = f2bf(p3);
    }

#pragma unroll
    for (int nt = 0; nt < 4; ++nt)
#pragma unroll
      for (int rg = 0; rg < 4; ++rg) o[nt][rg] *= alpha[rg];

    // P (A-frag) x V
    bf16x8 ap0 = __builtin_bit_cast(bf16x8, *(const ushortx8*)&Ps[wave][l16][quad * 8]);
    bf16x8 ap1 = __builtin_bit_cast(bf16x8, *(const ushortx8*)&Ps[wave][l16][32 + quad * 8]);
#pragma unroll
    for (int nt = 0; nt < 4; ++nt) {
      bf16x8 bv0 = __builtin_bit_cast(bf16x8, *(const ushortx8*)&Vt[cur][nt * 16 + l16][quad * 8]);
      bf16x8 bv1 = __builtin_bit_cast(bf16x8, *(const ushortx8*)&Vt[cur][nt * 16 + l16][32 + quad * 8]);
      o[nt] = __builtin_amdgcn_mfma_f32_16x16x32_bf16(ap0, bv0, o[nt], 0, 0, 0);
      o[nt] = __builtin_amdgcn_mfma_f32_16x16x32_bf16(ap1, bv1, o[nt], 0, 0, 0);
    }

    if (haveNext) {  // write prefetched tile into the other buffer
      int nb = cur ^ 1;
      *(ushortx8*)&Ks[nb][kkey][kd]     = kr0;
      *(ushortx8*)&Ks[nb][kkey][kd + 8] = kr1;
#pragma unroll
      for (int j = 0; j < 8; ++j) Vt[nb][wave * 16 + j][lane] = vr0[j];
#pragma unroll
      for (int j = 0; j < 8; ++j) Vt[nb][wave * 16 + 8 + j][lane] = vr1[j];
    }
    __syncthreads();  // single barrier per tile
  }

#pragma unroll
  for (int nt = 0; nt < 4; ++nt)
#pragma unroll
    for (int rg = 0; rg < 4; ++rg) {
      int qg = wq0 + quad * 4 + rg;
      int col = h * 64 + nt * 16 + l16;
      y[(size_t)(b * T + qg) * C + col] = f2bf(o[nt][rg] / lrun[rg]);
    }
}

extern "C" void kernel_launch(void* const* d_in, const int* in_sizes, int n_in,
                              void* d_out, int out_size, void* d_ws, size_t ws_size,
                              hipStream_t stream) {
  const float* x  = (const float*)d_in[0];
  const float* Wq = (const float*)d_in[1];
  const float* Wk = (const float*)d_in[2];
  const float* Wv = (const float*)d_in[3];
  const float* Wo = (const float*)d_in[4];
  // d_in[5] = mask: known causal tril, handled analytically

  char* ws = (char*)d_ws;
  float* partials = (float*)ws;             // 256 floats
  float* scales   = (float*)(ws + 1024);    // 4 floats
  u16* Wt = (u16*)(ws + 4096);              // 4 x 1M bf16 (ternary)
  u16* xb = (u16*)(ws + 4096 + (size_t)(8u << 20));   // x in bf16 (4M elems)
  u16* qb = xb + (4u << 20);
  u16* kb = qb + (4u << 20);
  u16* vb = kb + (4u << 20);
  u16* yb = vb + (4u << 20);
  float* out = (float*)d_out;  // reference output dtype is float32

  cvt_kernel<<<2048, 256, 0, stream>>>(x, xb);
  absum_kernel<<<dim3(64, 4), 256, 0, stream>>>(Wq, Wk, Wv, Wo, partials);
  scales_kernel<<<1, 64, 0, stream>>>(partials, scales);
  quant_kernel<<<dim3(4096, 4), 256, 0, stream>>>(Wq, Wk, Wv, Wo, scales, Wt);

  const int M = 4096, N = 1024, K = 1024;
  gemm_bt<false><<<dim3(64, 16), 256, 0, stream>>>(xb, Wt + 0 * (1u << 20), qb, M, N, K, scales + 0);
  gemm_bt<false><<<dim3(64, 16), 256, 0, stream>>>(xb, Wt + 1 * (1u << 20), kb, M, N, K, scales + 1);
  gemm_bt<false><<<dim3(64, 16), 256, 0, stream>>>(xb, Wt + 2 * (1u << 20), vb, M, N, K, scales + 2);
  rope_kernel<<<8192, 256, 0, stream>>>(qb, kb);
  attn_kernel<<<dim3(32, 32), 256, 0, stream>>>(qb, kb, vb, yb);
  gemm_bt<true><<<dim3(64, 16), 256, 0, stream>>>(yb, Wt + 3 * (1u << 20), out, M, N, K, scales + 3);
}

// Round 5
// 301.152 us; speedup vs baseline: 1.4866x; 1.1482x over previous
//
#include <hip/hip_runtime.h>
#include <math.h>

using bf16x8  = __attribute__((ext_vector_type(8))) __bf16;
using floatx4 = __attribute__((ext_vector_type(4))) float;
using ushortx8 = __attribute__((ext_vector_type(8))) unsigned short;
typedef unsigned short u16;

__device__ __forceinline__ float bf2f(u16 u) {
  unsigned int x = ((unsigned int)u) << 16;
  return __builtin_bit_cast(float, x);
}
__device__ __forceinline__ u16 f2bf(float f) {
  unsigned int x = __builtin_bit_cast(unsigned int, f);
  x += 0x7FFFu + ((x >> 16) & 1u);   // round-to-nearest-even
  return (u16)(x >> 16);
}

// 16-lane butterfly max via DPP (VALU only, no LDS pipe)
template <int CTRL>
__device__ __forceinline__ float dpp_fmax(float v) {
  int t = __builtin_amdgcn_update_dpp(0, __builtin_bit_cast(int, v), CTRL, 0xf, 0xf, true);
  return fmaxf(v, __builtin_bit_cast(float, t));
}
__device__ __forceinline__ float rowmax16(float v) {
  v = dpp_fmax<0xB1>(v);   // quad_perm [1,0,3,2] : xor1
  v = dpp_fmax<0x4E>(v);   // quad_perm [2,3,0,1] : xor2
  v = dpp_fmax<0x141>(v);  // row_half_mirror     : xor4-equivalent
  v = dpp_fmax<0x140>(v);  // row_mirror          : xor8-equivalent
  return v;
}

// ---------------- x: fp32 -> bf16 ----------------
__global__ __launch_bounds__(256) void cvt_kernel(const float* __restrict__ x, u16* __restrict__ xb) {
  int g = (blockIdx.x * 256 + threadIdx.x) * 8;
  float4 a = *(const float4*)(x + g);
  float4 b = *(const float4*)(x + g + 4);
  ushortx8 o;
  o[0] = f2bf(a.x); o[1] = f2bf(a.y); o[2] = f2bf(a.z); o[3] = f2bf(a.w);
  o[4] = f2bf(b.x); o[5] = f2bf(b.y); o[6] = f2bf(b.z); o[7] = f2bf(b.w);
  *(ushortx8*)(xb + g) = o;
}

// ---------------- weight scale: sum |W| ----------------
__global__ __launch_bounds__(256) void absum_kernel(const float* W0, const float* W1,
                                                    const float* W2, const float* W3,
                                                    float* partials) {
  const float* W = (blockIdx.y == 0) ? W0 : (blockIdx.y == 1) ? W1 : (blockIdx.y == 2) ? W2 : W3;
  int tid = threadIdx.x;
  int base = blockIdx.x * 16384 + tid;
  float s = 0.f;
#pragma unroll
  for (int i = 0; i < 64; ++i) s += fabsf(W[base + i * 256]);
  __shared__ float red[256];
  red[tid] = s;
  __syncthreads();
  for (int off = 128; off > 0; off >>= 1) {
    if (tid < off) red[tid] += red[tid + off];
    __syncthreads();
  }
  if (tid == 0) partials[blockIdx.y * 64 + blockIdx.x] = red[0];
}

__global__ void scales_kernel(const float* partials, float* scales) {
  int w = threadIdx.x;
  if (w < 4) {
    float s = 0.f;
    for (int i = 0; i < 64; ++i) s += partials[w * 64 + i];
    scales[w] = s * (1.f / 1048576.f);
  }
}

// ---------------- ternary quantize ----------------
__global__ __launch_bounds__(256) void quant_kernel(const float* W0, const float* W1,
                                                    const float* W2, const float* W3,
                                                    const float* scales, u16* Wt) {
  int w = blockIdx.y;
  const float* W = (w == 0) ? W0 : (w == 1) ? W1 : (w == 2) ? W2 : W3;
  u16* O = Wt + (size_t)w * (1u << 20);
  float s = scales[w] + 1e-8f;
  int e = blockIdx.x * 256 + threadIdx.x;
  float t = W[e] / s;
  t = fminf(fmaxf(t, -1.f), 1.f);
  O[e] = f2bf(rintf(t));
}

// ---------------- GEMM v2: 128x64 tile, BK=64, global_load_lds staging ----------------
// C[M,N] = (A[M,K] * B[N,K]^T) * scale
template <bool OUT_F32>
__global__ __launch_bounds__(256) void gemm_bt(const u16* __restrict__ A, const u16* __restrict__ B,
                                               void* __restrict__ Cv, int M, int N, int K,
                                               const float* __restrict__ scale_ptr) {
  __shared__ __align__(16) u16 As[128][64];  // 16 KB, NO padding (glds lane-contiguity)
  __shared__ __align__(16) u16 Bs[64][64];   // 8 KB
  int tid = threadIdx.x;
  int wave = tid >> 6, lane = tid & 63;
  int quad = lane >> 4, l16 = lane & 15;
  int bm = blockIdx.x * 128, bn = blockIdx.y * 64;
  int wm = (wave >> 1) * 64, wn = (wave & 1) * 32;
  floatx4 acc[4][2] = {};
  // glds source: lane l -> row +(l>>3), col (l&7)*8 (matches LDS dest = base + l*16B)
  const u16* ga = A + (size_t)(bm + wave * 32 + (lane >> 3)) * K + (lane & 7) * 8;
  const u16* gb = B + (size_t)(bn + wave * 16 + (lane >> 3)) * K + (lane & 7) * 8;
  for (int k0 = 0; k0 < K; k0 += 64) {
    __syncthreads();  // protect LDS from overwrite while prior MFMA reads finish
#pragma unroll
    for (int i = 0; i < 4; ++i)
      __builtin_amdgcn_global_load_lds(
          (const __attribute__((address_space(1))) void*)(ga + (size_t)i * 8 * K + k0),
          (__attribute__((address_space(3))) void*)(&As[wave * 32 + i * 8][0]), 16, 0, 0);
#pragma unroll
    for (int i = 0; i < 2; ++i)
      __builtin_amdgcn_global_load_lds(
          (const __attribute__((address_space(1))) void*)(gb + (size_t)i * 8 * K + k0),
          (__attribute__((address_space(3))) void*)(&Bs[wave * 16 + i * 8][0]), 16, 0, 0);
    __syncthreads();  // drains vmcnt -> staged data visible
#pragma unroll
    for (int kk = 0; kk < 64; kk += 32) {
      bf16x8 a[4], b[2];
#pragma unroll
      for (int i = 0; i < 4; ++i)
        a[i] = __builtin_bit_cast(bf16x8, *(const ushortx8*)&As[wm + i * 16 + l16][kk + quad * 8]);
#pragma unroll
      for (int j = 0; j < 2; ++j)
        b[j] = __builtin_bit_cast(bf16x8, *(const ushortx8*)&Bs[wn + j * 16 + l16][kk + quad * 8]);
#pragma unroll
      for (int i = 0; i < 4; ++i)
#pragma unroll
        for (int j = 0; j < 2; ++j)
          acc[i][j] = __builtin_amdgcn_mfma_f32_16x16x32_bf16(a[i], b[j], acc[i][j], 0, 0, 0);
    }
  }
  float sc = scale_ptr[0];
#pragma unroll
  for (int i = 0; i < 4; ++i)
#pragma unroll
    for (int j = 0; j < 2; ++j)
#pragma unroll
      for (int rg = 0; rg < 4; ++rg) {
        int row = bm + wm + i * 16 + quad * 4 + rg;
        int col = bn + wn + j * 16 + l16;
        if (OUT_F32)
          ((float*)Cv)[(size_t)row * N + col] = acc[i][j][rg] * sc;
        else
          ((u16*)Cv)[(size_t)row * N + col] = f2bf(acc[i][j][rg] * sc);
      }
}

// ---------------- RoPE; folds (1/sqrt(64))*log2(e) into q -> softmax in log2 space ----------------
__global__ __launch_bounds__(256) void rope_kernel(u16* q, u16* k) {
  const float QS = 0.125f * 1.4426950408889634f;
  int gid = blockIdx.x * 256 + threadIdx.x;
  int i = gid & 31;
  int h = (gid >> 5) & 15;
  int bt = gid >> 9;
  int t = bt & 2047;
  float inv = exp2f(-(float)i * (13.287712379549449f / 32.f));
  float ang = (float)t * inv;
  float s = __sinf(ang), c = __cosf(ang);
  int row = bt * 1024 + h * 64;
  float q1 = bf2f(q[row + i]), q2 = bf2f(q[row + i + 32]);
  q[row + i]      = f2bf((q1 * c - q2 * s) * QS);
  q[row + i + 32] = f2bf((q2 * c + q1 * s) * QS);
  float k1 = bf2f(k[row + i]), k2 = bf2f(k[row + i + 32]);
  k[row + i]      = f2bf(k1 * c - k2 * s);
  k[row + i + 32] = f2bf(k2 * c + k1 * s);
}

// ---------------- causal flash attention v3 ----------------
// 64q block, 64-key tiles, dbuf K/V, DPP row-max, l accumulated via P*ones MFMA.
__global__ __launch_bounds__(256) void attn_kernel(const u16* __restrict__ q, const u16* __restrict__ k,
                                                   const u16* __restrict__ v, u16* __restrict__ y) {
  __shared__ __align__(16) u16 Ks[2][64][72];
  __shared__ __align__(16) u16 Vt[2][64][72];
  __shared__ __align__(16) u16 Ps[4][16][72];
  const int T = 2048, C = 1024;
  int tid = threadIdx.x;
  int wave = tid >> 6, lane = tid & 63;
  int quad = lane >> 4, l16 = lane & 15;
  int qblock = (int)gridDim.x - 1 - (int)blockIdx.x;  // heavy blocks first
  int q0 = qblock * 64;
  int b = blockIdx.y >> 4, h = blockIdx.y & 15;
  int wq0 = q0 + wave * 16;

  const u16* gq = q + (size_t)(b * T + wq0 + l16) * C + h * 64 + quad * 8;
  bf16x8 aq0 = __builtin_bit_cast(bf16x8, *(const ushortx8*)(gq));
  bf16x8 aq1 = __builtin_bit_cast(bf16x8, *(const ushortx8*)(gq + 32));

  ushortx8 onesu;
#pragma unroll
  for (int j = 0; j < 8; ++j) onesu[j] = 0x3F80;  // bf16 1.0
  bf16x8 bones = __builtin_bit_cast(bf16x8, onesu);

  int kkey = tid >> 2, kd = (tid & 3) << 4;
  const u16* kbase = k + (size_t)(b * T + kkey) * C + h * 64 + kd;
  const u16* vbase = v + (size_t)(b * T + lane) * C + h * 64 + wave * 16;

  float mrun[4];
  floatx4 o[5] = {};  // o[4] = row-sum accumulator (l)
#pragma unroll
  for (int rg = 0; rg < 4; ++rg) mrun[rg] = -__builtin_inff();

  int nkt = qblock + 1;

  ushortx8 kr0 = *(const ushortx8*)(kbase);
  ushortx8 kr1 = *(const ushortx8*)(kbase + 8);
  ushortx8 vr0 = *(const ushortx8*)(vbase);
  ushortx8 vr1 = *(const ushortx8*)(vbase + 8);
  *(ushortx8*)&Ks[0][kkey][kd]     = kr0;
  *(ushortx8*)&Ks[0][kkey][kd + 8] = kr1;
#pragma unroll
  for (int j = 0; j < 8; ++j) Vt[0][wave * 16 + j][lane] = vr0[j];
#pragma unroll
  for (int j = 0; j < 8; ++j) Vt[0][wave * 16 + 8 + j][lane] = vr1[j];
  __syncthreads();

  for (int kt = 0; kt < nkt; ++kt) {
    int cur = kt & 1;
    bool haveNext = (kt + 1) < nkt;
    if (haveNext) {
      const u16* kn = kbase + (size_t)(kt + 1) * 64 * C;
      const u16* vn = vbase + (size_t)(kt + 1) * 64 * C;
      kr0 = *(const ushortx8*)(kn);
      kr1 = *(const ushortx8*)(kn + 8);
      vr0 = *(const ushortx8*)(vn);
      vr1 = *(const ushortx8*)(vn + 8);
    }

    // S = Q K^T, already in log2 units (scale folded into q)
    floatx4 sacc[4] = {};
#pragma unroll
    for (int nt = 0; nt < 4; ++nt) {
      bf16x8 bk0 = __builtin_bit_cast(bf16x8, *(const ushortx8*)&Ks[cur][nt * 16 + l16][quad * 8]);
      bf16x8 bk1 = __builtin_bit_cast(bf16x8, *(const ushortx8*)&Ks[cur][nt * 16 + l16][32 + quad * 8]);
      sacc[nt] = __builtin_amdgcn_mfma_f32_16x16x32_bf16(aq0, bk0, sacc[nt], 0, 0, 0);
      sacc[nt] = __builtin_amdgcn_mfma_f32_16x16x32_bf16(aq1, bk1, sacc[nt], 0, 0, 0);
    }

    bool last = (kt == nkt - 1);
    float alpha[4];
#pragma unroll
    for (int rg = 0; rg < 4; ++rg) {
      float s0 = sacc[0][rg], s1 = sacc[1][rg], s2 = sacc[2][rg], s3 = sacc[3][rg];
      if (last) {
        int qr = wq0 + quad * 4 + rg;
        int key = kt * 64 + l16;
        if (key      > qr) s0 = -__builtin_inff();
        if (key + 16 > qr) s1 = -__builtin_inff();
        if (key + 32 > qr) s2 = -__builtin_inff();
        if (key + 48 > qr) s3 = -__builtin_inff();
      }
      float mx = fmaxf(fmaxf(s0, s1), fmaxf(s2, s3));
      mx = rowmax16(mx);          // DPP butterfly across the 16 col-lanes
      mx = fmaxf(mx, mrun[rg]);
      alpha[rg] = exp2f(mrun[rg] - mx);
      mrun[rg] = mx;
      Ps[wave][quad * 4 + rg][l16]      = f2bf(exp2f(s0 - mx));
      Ps[wave][quad * 4 + rg][16 + l16] = f2bf(exp2f(s1 - mx));
      Ps[wave][quad * 4 + rg][32 + l16] = f2bf(exp2f(s2 - mx));
      Ps[wave][quad * 4 + rg][48 + l16] = f2bf(exp2f(s3 - mx));
    }

#pragma unroll
    for (int nt = 0; nt < 5; ++nt)
#pragma unroll
      for (int rg = 0; rg < 4; ++rg) o[nt][rg] *= alpha[rg];

    bf16x8 ap0 = __builtin_bit_cast(bf16x8, *(const ushortx8*)&Ps[wave][l16][quad * 8]);
    bf16x8 ap1 = __builtin_bit_cast(bf16x8, *(const ushortx8*)&Ps[wave][l16][32 + quad * 8]);
#pragma unroll
    for (int nt = 0; nt < 4; ++nt) {
      bf16x8 bv0 = __builtin_bit_cast(bf16x8, *(const ushortx8*)&Vt[cur][nt * 16 + l16][quad * 8]);
      bf16x8 bv1 = __builtin_bit_cast(bf16x8, *(const ushortx8*)&Vt[cur][nt * 16 + l16][32 + quad * 8]);
      o[nt] = __builtin_amdgcn_mfma_f32_16x16x32_bf16(ap0, bv0, o[nt], 0, 0, 0);
      o[nt] = __builtin_amdgcn_mfma_f32_16x16x32_bf16(ap1, bv1, o[nt], 0, 0, 0);
    }
    o[4] = __builtin_amdgcn_mfma_f32_16x16x32_bf16(ap0, bones, o[4], 0, 0, 0);  // row sums (l)
    o[4] = __builtin_amdgcn_mfma_f32_16x16x32_bf16(ap1, bones, o[4], 0, 0, 0);

    if (haveNext) {
      int nb = cur ^ 1;
      *(ushortx8*)&Ks[nb][kkey][kd]     = kr0;
      *(ushortx8*)&Ks[nb][kkey][kd + 8] = kr1;
#pragma unroll
      for (int j = 0; j < 8; ++j) Vt[nb][wave * 16 + j][lane] = vr0[j];
#pragma unroll
      for (int j = 0; j < 8; ++j) Vt[nb][wave * 16 + 8 + j][lane] = vr1[j];
    }
    __syncthreads();
  }

#pragma unroll
  for (int nt = 0; nt < 4; ++nt)
#pragma unroll
    for (int rg = 0; rg < 4; ++rg) {
      int qg = wq0 + quad * 4 + rg;
      int col = h * 64 + nt * 16 + l16;
      y[(size_t)(b * T + qg) * C + col] = f2bf(o[nt][rg] / o[4][rg]);
    }
}

extern "C" void kernel_launch(void* const* d_in, const int* in_sizes, int n_in,
                              void* d_out, int out_size, void* d_ws, size_t ws_size,
                              hipStream_t stream) {
  const float* x  = (const float*)d_in[0];
  const float* Wq = (const float*)d_in[1];
  const float* Wk = (const float*)d_in[2];
  const float* Wv = (const float*)d_in[3];
  const float* Wo = (const float*)d_in[4];

  char* ws = (char*)d_ws;
  float* partials = (float*)ws;
  float* scales   = (float*)(ws + 1024);
  u16* Wt = (u16*)(ws + 4096);
  u16* xb = (u16*)(ws + 4096 + (size_t)(8u << 20));
  u16* qb = xb + (4u << 20);
  u16* kb = qb + (4u << 20);
  u16* vb = kb + (4u << 20);
  u16* yb = vb + (4u << 20);
  float* out = (float*)d_out;

  cvt_kernel<<<2048, 256, 0, stream>>>(x, xb);
  absum_kernel<<<dim3(64, 4), 256, 0, stream>>>(Wq, Wk, Wv, Wo, partials);
  scales_kernel<<<1, 64, 0, stream>>>(partials, scales);
  quant_kernel<<<dim3(4096, 4), 256, 0, stream>>>(Wq, Wk, Wv, Wo, scales, Wt);

  const int M = 4096, N = 1024, K = 1024;
  gemm_bt<false><<<dim3(32, 16), 256, 0, stream>>>(xb, Wt + 0 * (1u << 20), qb, M, N, K, scales + 0);
  gemm_bt<false><<<dim3(32, 16), 256, 0, stream>>>(xb, Wt + 1 * (1u << 20), kb, M, N, K, scales + 1);
  gemm_bt<false><<<dim3(32, 16), 256, 0, stream>>>(xb, Wt + 2 * (1u << 20), vb, M, N, K, scales + 2);
  rope_kernel<<<8192, 256, 0, stream>>>(qb, kb);
  attn_kernel<<<dim3(32, 32), 256, 0, stream>>>(qb, kb, vb, yb);
  gemm_bt<true><<<dim3(32, 16), 256, 0, stream>>>(yb, Wt + 3 * (1u << 20), out, M, N, K, scales + 3);
}

// Round 6
// 247.999 us; speedup vs baseline: 1.8052x; 1.2143x over previous
//
#include <hip/hip_runtime.h>
#include <math.h>

using bf16x8  = __attribute__((ext_vector_type(8))) __bf16;
using floatx4 = __attribute__((ext_vector_type(4))) float;
using ushortx8 = __attribute__((ext_vector_type(8))) unsigned short;
typedef unsigned short u16;

__device__ __forceinline__ float bf2f(u16 u) {
  unsigned int x = ((unsigned int)u) << 16;
  return __builtin_bit_cast(float, x);
}
__device__ __forceinline__ u16 f2bf(float f) {
  unsigned int x = __builtin_bit_cast(unsigned int, f);
  x += 0x7FFFu + ((x >> 16) & 1u);   // round-to-nearest-even
  return (u16)(x >> 16);
}
__device__ __forceinline__ float fexp2(float x) { return __builtin_amdgcn_exp2f(x); }

// ---------------- x: fp32 -> bf16 ----------------
__global__ __launch_bounds__(256) void cvt_kernel(const float* __restrict__ x, u16* __restrict__ xb) {
  int g = (blockIdx.x * 256 + threadIdx.x) * 8;
  float4 a = *(const float4*)(x + g);
  float4 b = *(const float4*)(x + g + 4);
  ushortx8 o;
  o[0] = f2bf(a.x); o[1] = f2bf(a.y); o[2] = f2bf(a.z); o[3] = f2bf(a.w);
  o[4] = f2bf(b.x); o[5] = f2bf(b.y); o[6] = f2bf(b.z); o[7] = f2bf(b.w);
  *(ushortx8*)(xb + g) = o;
}

// ---------------- weight scale: sum |W| ----------------
__global__ __launch_bounds__(256) void absum_kernel(const float* W0, const float* W1,
                                                    const float* W2, const float* W3,
                                                    float* partials) {
  const float* W = (blockIdx.y == 0) ? W0 : (blockIdx.y == 1) ? W1 : (blockIdx.y == 2) ? W2 : W3;
  int tid = threadIdx.x;
  int base = blockIdx.x * 16384 + tid;
  float s = 0.f;
#pragma unroll
  for (int i = 0; i < 64; ++i) s += fabsf(W[base + i * 256]);
  __shared__ float red[256];
  red[tid] = s;
  __syncthreads();
  for (int off = 128; off > 0; off >>= 1) {
    if (tid < off) red[tid] += red[tid + off];
    __syncthreads();
  }
  if (tid == 0) partials[blockIdx.y * 64 + blockIdx.x] = red[0];
}

__global__ void scales_kernel(const float* partials, float* scales) {
  int w = threadIdx.x;
  if (w < 4) {
    float s = 0.f;
    for (int i = 0; i < 64; ++i) s += partials[w * 64 + i];
    scales[w] = s * (1.f / 1048576.f);
  }
}

// ---------------- ternary quantize ----------------
__global__ __launch_bounds__(256) void quant_kernel(const float* W0, const float* W1,
                                                    const float* W2, const float* W3,
                                                    const float* scales, u16* Wt) {
  int w = blockIdx.y;
  const float* W = (w == 0) ? W0 : (w == 1) ? W1 : (w == 2) ? W2 : W3;
  u16* O = Wt + (size_t)w * (1u << 20);
  float s = scales[w] + 1e-8f;
  int e = blockIdx.x * 256 + threadIdx.x;
  float t = W[e] / s;
  t = fminf(fmaxf(t, -1.f), 1.f);
  O[e] = f2bf(rintf(t));
}

// ---------------- fused QKV GEMM: C[4096,3072] = xb * [Wq;Wk;Wv]^T, routed to qb/kb/vb ----------------
__global__ __launch_bounds__(256) void gemm_qkv(const u16* __restrict__ A, const u16* __restrict__ Wt,
                                                u16* __restrict__ QKV, const float* __restrict__ scales) {
  const int K = 1024;
  __shared__ __align__(16) u16 As[128][64];
  __shared__ __align__(16) u16 Bs[64][64];
  int tid = threadIdx.x;
  int wave = tid >> 6, lane = tid & 63;
  int quad = lane >> 4, l16 = lane & 15;
  int bm = blockIdx.x * 128;
  int bnc = blockIdx.y * 64;           // 0..3071 across the 3 stacked weight matrices
  int mat = bnc >> 10, bn = bnc & 1023;
  int wm = (wave >> 1) * 64, wn = (wave & 1) * 32;
  floatx4 acc[4][2] = {};
  const u16* ga = A  + (size_t)(bm + wave * 32 + (lane >> 3)) * K + (lane & 7) * 8;
  const u16* gb = Wt + (size_t)(bnc + wave * 16 + (lane >> 3)) * K + (lane & 7) * 8;
  for (int k0 = 0; k0 < K; k0 += 64) {
    __syncthreads();
#pragma unroll
    for (int i = 0; i < 4; ++i)
      __builtin_amdgcn_global_load_lds(
          (const __attribute__((address_space(1))) void*)(ga + (size_t)i * 8 * K + k0),
          (__attribute__((address_space(3))) void*)(&As[wave * 32 + i * 8][0]), 16, 0, 0);
#pragma unroll
    for (int i = 0; i < 2; ++i)
      __builtin_amdgcn_global_load_lds(
          (const __attribute__((address_space(1))) void*)(gb + (size_t)i * 8 * K + k0),
          (__attribute__((address_space(3))) void*)(&Bs[wave * 16 + i * 8][0]), 16, 0, 0);
    __syncthreads();
#pragma unroll
    for (int kk = 0; kk < 64; kk += 32) {
      bf16x8 a[4], b[2];
#pragma unroll
      for (int i = 0; i < 4; ++i)
        a[i] = __builtin_bit_cast(bf16x8, *(const ushortx8*)&As[wm + i * 16 + l16][kk + quad * 8]);
#pragma unroll
      for (int j = 0; j < 2; ++j)
        b[j] = __builtin_bit_cast(bf16x8, *(const ushortx8*)&Bs[wn + j * 16 + l16][kk + quad * 8]);
#pragma unroll
      for (int i = 0; i < 4; ++i)
#pragma unroll
        for (int j = 0; j < 2; ++j)
          acc[i][j] = __builtin_amdgcn_mfma_f32_16x16x32_bf16(a[i], b[j], acc[i][j], 0, 0, 0);
    }
  }
  float sc = scales[mat];
  u16* out = QKV + (size_t)mat * (4u << 20);
#pragma unroll
  for (int i = 0; i < 4; ++i)
#pragma unroll
    for (int j = 0; j < 2; ++j)
#pragma unroll
      for (int rg = 0; rg < 4; ++rg) {
        int row = bm + wm + i * 16 + quad * 4 + rg;
        int col = bn + wn + j * 16 + l16;
        out[(size_t)row * 1024 + col] = f2bf(acc[i][j][rg] * sc);
      }
}

// ---------------- output projection GEMM (fp32 out) ----------------
__global__ __launch_bounds__(256) void gemm_out(const u16* __restrict__ A, const u16* __restrict__ B,
                                                float* __restrict__ C, const float* __restrict__ scale_ptr) {
  const int K = 1024, N = 1024;
  __shared__ __align__(16) u16 As[128][64];
  __shared__ __align__(16) u16 Bs[64][64];
  int tid = threadIdx.x;
  int wave = tid >> 6, lane = tid & 63;
  int quad = lane >> 4, l16 = lane & 15;
  int bm = blockIdx.x * 128, bn = blockIdx.y * 64;
  int wm = (wave >> 1) * 64, wn = (wave & 1) * 32;
  floatx4 acc[4][2] = {};
  const u16* ga = A + (size_t)(bm + wave * 32 + (lane >> 3)) * K + (lane & 7) * 8;
  const u16* gb = B + (size_t)(bn + wave * 16 + (lane >> 3)) * K + (lane & 7) * 8;
  for (int k0 = 0; k0 < K; k0 += 64) {
    __syncthreads();
#pragma unroll
    for (int i = 0; i < 4; ++i)
      __builtin_amdgcn_global_load_lds(
          (const __attribute__((address_space(1))) void*)(ga + (size_t)i * 8 * K + k0),
          (__attribute__((address_space(3))) void*)(&As[wave * 32 + i * 8][0]), 16, 0, 0);
#pragma unroll
    for (int i = 0; i < 2; ++i)
      __builtin_amdgcn_global_load_lds(
          (const __attribute__((address_space(1))) void*)(gb + (size_t)i * 8 * K + k0),
          (__attribute__((address_space(3))) void*)(&Bs[wave * 16 + i * 8][0]), 16, 0, 0);
    __syncthreads();
#pragma unroll
    for (int kk = 0; kk < 64; kk += 32) {
      bf16x8 a[4], b[2];
#pragma unroll
      for (int i = 0; i < 4; ++i)
        a[i] = __builtin_bit_cast(bf16x8, *(const ushortx8*)&As[wm + i * 16 + l16][kk + quad * 8]);
#pragma unroll
      for (int j = 0; j < 2; ++j)
        b[j] = __builtin_bit_cast(bf16x8, *(const ushortx8*)&Bs[wn + j * 16 + l16][kk + quad * 8]);
#pragma unroll
      for (int i = 0; i < 4; ++i)
#pragma unroll
        for (int j = 0; j < 2; ++j)
          acc[i][j] = __builtin_amdgcn_mfma_f32_16x16x32_bf16(a[i], b[j], acc[i][j], 0, 0, 0);
    }
  }
  float sc = scale_ptr[0];
#pragma unroll
  for (int i = 0; i < 4; ++i)
#pragma unroll
    for (int j = 0; j < 2; ++j)
#pragma unroll
      for (int rg = 0; rg < 4; ++rg) {
        int row = bm + wm + i * 16 + quad * 4 + rg;
        int col = bn + wn + j * 16 + l16;
        C[(size_t)row * N + col] = acc[i][j][rg] * sc;
      }
}

// ---------------- RoPE; folds (1/sqrt(64))*log2(e) into q ----------------
__global__ __launch_bounds__(256) void rope_kernel(u16* q, u16* k) {
  const float QS = 0.125f * 1.4426950408889634f;
  int gid = blockIdx.x * 256 + threadIdx.x;
  int i = gid & 31;
  int h = (gid >> 5) & 15;
  int bt = gid >> 9;
  int t = bt & 2047;
  float inv = exp2f(-(float)i * (13.287712379549449f / 32.f));
  float ang = (float)t * inv;
  float s = __sinf(ang), c = __cosf(ang);
  int row = bt * 1024 + h * 64;
  float q1 = bf2f(q[row + i]), q2 = bf2f(q[row + i + 32]);
  q[row + i]      = f2bf((q1 * c - q2 * s) * QS);
  q[row + i + 32] = f2bf((q2 * c + q1 * s) * QS);
  float k1 = bf2f(k[row + i]), k2 = bf2f(k[row + i + 32]);
  k[row + i]      = f2bf(k1 * c - k2 * s);
  k[row + i + 32] = f2bf(k2 * c + k1 * s);
}

// ---------------- causal flash attention v4 ----------------
// 128-q block (8 waves x 16q sharing K/V staging), 64-key tiles, dbuf, S^T softmax
// (per-lane q row: in-lane max + 2 shuffles), l via P*ones MFMA, vectorized Ps.
__global__ __launch_bounds__(512, 4) void attn_kernel(const u16* __restrict__ q, const u16* __restrict__ k,
                                                      const u16* __restrict__ v, u16* __restrict__ y) {
  __shared__ __align__(16) u16 Ks[2][64][72];
  __shared__ __align__(16) u16 Vt[2][64][72];
  __shared__ __align__(16) u16 Ps[8][16][72];
  const int T = 2048, C = 1024;
  int tid = threadIdx.x;
  int wave = tid >> 6, lane = tid & 63;
  int quad = lane >> 4, l16 = lane & 15;
  int p = (int)gridDim.x - 1 - (int)blockIdx.x;  // heavy blocks first
  int q0 = p * 128;
  int b = blockIdx.y >> 4, h = blockIdx.y & 15;
  int wq0 = q0 + wave * 16;
  int nkt = 2 * p + 2;       // 64-key tiles covering [0, q0+128)
  int dtile = wq0 >> 6;      // this wave's diagonal tile

  const u16* gq = q + (size_t)(b * T + wq0 + l16) * C + h * 64 + quad * 8;
  bf16x8 bq0 = __builtin_bit_cast(bf16x8, *(const ushortx8*)(gq));       // Q as B-operand
  bf16x8 bq1 = __builtin_bit_cast(bf16x8, *(const ushortx8*)(gq + 32));

  ushortx8 onesu;
#pragma unroll
  for (int j = 0; j < 8; ++j) onesu[j] = 0x3F80;  // bf16 1.0
  bf16x8 bones = __builtin_bit_cast(bf16x8, onesu);

  int krow = tid >> 3, kcol = (tid & 7) * 8;
  const u16* kptr = k + (size_t)(b * T + krow) * C + h * 64 + kcol;
  int vkey = tid & 63, vd = (tid >> 6) * 8;
  const u16* vptr = v + (size_t)(b * T + vkey) * C + h * 64 + vd;

  float mrun = -__builtin_inff();  // per-lane: q = wq0 + l16
  floatx4 o[5] = {};               // o[4] = row-sum (l)

  ushortx8 kr = *(const ushortx8*)kptr;
  ushortx8 vr = *(const ushortx8*)vptr;
  *(ushortx8*)&Ks[0][krow][kcol] = kr;
#pragma unroll
  for (int j = 0; j < 8; ++j) Vt[0][vd + j][vkey] = vr[j];
  __syncthreads();

  for (int kt = 0; kt < nkt; ++kt) {
    int cur = kt & 1;
    bool haveNext = (kt + 1) < nkt;
    if (haveNext) {
      kr = *(const ushortx8*)(kptr + (size_t)(kt + 1) * 64 * C);
      vr = *(const ushortx8*)(vptr + (size_t)(kt + 1) * 64 * C);
    }

    if (wave >= 4 || kt < nkt - 1) {  // lower-half waves skip the final (fully-masked) tile
      // S^T = K Q^T : lane holds S[q=l16][key = kt*64 + nt*16 + quad*4 + rg]
      floatx4 sacc[4] = {};
#pragma unroll
      for (int nt = 0; nt < 4; ++nt) {
        bf16x8 ak0 = __builtin_bit_cast(bf16x8, *(const ushortx8*)&Ks[cur][nt * 16 + l16][quad * 8]);
        bf16x8 ak1 = __builtin_bit_cast(bf16x8, *(const ushortx8*)&Ks[cur][nt * 16 + l16][32 + quad * 8]);
        sacc[nt] = __builtin_amdgcn_mfma_f32_16x16x32_bf16(ak0, bq0, sacc[nt], 0, 0, 0);
        sacc[nt] = __builtin_amdgcn_mfma_f32_16x16x32_bf16(ak1, bq1, sacc[nt], 0, 0, 0);
      }

      if (kt == dtile) {  // causal mask, diagonal tile only
        int qg = wq0 + l16;
#pragma unroll
        for (int nt = 0; nt < 4; ++nt)
#pragma unroll
          for (int rg = 0; rg < 4; ++rg)
            if (kt * 64 + nt * 16 + quad * 4 + rg > qg) sacc[nt][rg] = -__builtin_inff();
      }

      // row max: in-lane tree + butterfly over the 4 quads
      float mx = fmaxf(fmaxf(sacc[0][0], sacc[0][1]), fmaxf(sacc[0][2], sacc[0][3]));
#pragma unroll
      for (int nt = 1; nt < 4; ++nt) {
        float m2 = fmaxf(fmaxf(sacc[nt][0], sacc[nt][1]), fmaxf(sacc[nt][2], sacc[nt][3]));
        mx = fmaxf(mx, m2);
      }
      mx = fmaxf(mx, __shfl_xor(mx, 16, 64));
      mx = fmaxf(mx, __shfl_xor(mx, 32, 64));
      mx = fmaxf(mx, mrun);
      float alpha = fexp2(mrun - mx);
      mrun = mx;

      // P^T -> bf16, vectorized store: lane writes 4 keys for its q
#pragma unroll
      for (int nt = 0; nt < 4; ++nt) {
        unsigned lo = (unsigned)f2bf(fexp2(sacc[nt][0] - mx)) |
                      ((unsigned)f2bf(fexp2(sacc[nt][1] - mx)) << 16);
        unsigned hi = (unsigned)f2bf(fexp2(sacc[nt][2] - mx)) |
                      ((unsigned)f2bf(fexp2(sacc[nt][3] - mx)) << 16);
        *(uint2*)&Ps[wave][l16][nt * 16 + quad * 4] = make_uint2(lo, hi);
      }

      // rescale O (rows q = quad*4+rg) by that row's alpha
      float ar[4];
#pragma unroll
      for (int rg = 0; rg < 4; ++rg) ar[rg] = __shfl(alpha, quad * 4 + rg, 64);
#pragma unroll
      for (int a = 0; a < 5; ++a)
#pragma unroll
        for (int rg = 0; rg < 4; ++rg) o[a][rg] *= ar[rg];

      // P (A-frag) x V
      bf16x8 ap0 = __builtin_bit_cast(bf16x8, *(const ushortx8*)&Ps[wave][l16][quad * 8]);
      bf16x8 ap1 = __builtin_bit_cast(bf16x8, *(const ushortx8*)&Ps[wave][l16][32 + quad * 8]);
#pragma unroll
      for (int nt = 0; nt < 4; ++nt) {
        bf16x8 bv0 = __builtin_bit_cast(bf16x8, *(const ushortx8*)&Vt[cur][nt * 16 + l16][quad * 8]);
        bf16x8 bv1 = __builtin_bit_cast(bf16x8, *(const ushortx8*)&Vt[cur][nt * 16 + l16][32 + quad * 8]);
        o[nt] = __builtin_amdgcn_mfma_f32_16x16x32_bf16(ap0, bv0, o[nt], 0, 0, 0);
        o[nt] = __builtin_amdgcn_mfma_f32_16x16x32_bf16(ap1, bv1, o[nt], 0, 0, 0);
      }
      o[4] = __builtin_amdgcn_mfma_f32_16x16x32_bf16(ap0, bones, o[4], 0, 0, 0);
      o[4] = __builtin_amdgcn_mfma_f32_16x16x32_bf16(ap1, bones, o[4], 0, 0, 0);
    }

    if (haveNext) {
      int nb = cur ^ 1;
      *(ushortx8*)&Ks[nb][krow][kcol] = kr;
#pragma unroll
      for (int j = 0; j < 8; ++j) Vt[nb][vd + j][vkey] = vr[j];
    }
    __syncthreads();  // single barrier per tile
  }

#pragma unroll
  for (int nt = 0; nt < 4; ++nt)
#pragma unroll
    for (int rg = 0; rg < 4; ++rg) {
      int qg = wq0 + quad * 4 + rg;
      int col = h * 64 + nt * 16 + l16;
      y[(size_t)(b * T + qg) * C + col] = f2bf(o[nt][rg] / o[4][rg]);
    }
}

extern "C" void kernel_launch(void* const* d_in, const int* in_sizes, int n_in,
                              void* d_out, int out_size, void* d_ws, size_t ws_size,
                              hipStream_t stream) {
  const float* x  = (const float*)d_in[0];
  const float* Wq = (const float*)d_in[1];
  const float* Wk = (const float*)d_in[2];
  const float* Wv = (const float*)d_in[3];
  const float* Wo = (const float*)d_in[4];

  char* ws = (char*)d_ws;
  float* partials = (float*)ws;
  float* scales   = (float*)(ws + 1024);
  u16* Wt = (u16*)(ws + 4096);                        // 4 x 1M bf16 ternary (Q,K,V,O stacked)
  u16* xb = (u16*)(ws + 4096 + (size_t)(8u << 20));
  u16* qb = xb + (4u << 20);                          // qb,kb,vb contiguous (fused epilogue relies on it)
  u16* kb = qb + (4u << 20);
  u16* vb = kb + (4u << 20);
  u16* yb = vb + (4u << 20);
  float* out = (float*)d_out;

  cvt_kernel<<<2048, 256, 0, stream>>>(x, xb);
  absum_kernel<<<dim3(64, 4), 256, 0, stream>>>(Wq, Wk, Wv, Wo, partials);
  scales_kernel<<<1, 64, 0, stream>>>(partials, scales);
  quant_kernel<<<dim3(4096, 4), 256, 0, stream>>>(Wq, Wk, Wv, Wo, scales, Wt);

  gemm_qkv<<<dim3(32, 48), 256, 0, stream>>>(xb, Wt, qb, scales);
  rope_kernel<<<8192, 256, 0, stream>>>(qb, kb);
  attn_kernel<<<dim3(16, 32), 512, 0, stream>>>(qb, kb, vb, yb);
  gemm_out<<<dim3(32, 16), 256, 0, stream>>>(yb, Wt + 3 * (1u << 20), out, scales + 3);
}